// Round 7
// baseline (429.492 us; speedup 1.0000x reference)
//
#include <hip/hip_runtime.h>

// ---------------------------------------------------------------------------
// B=8, S=4096 (rows=32768), D=1024, DS=64
// segments: qk 512 (tiles 0-31) | v 256 (32-47) | rel 128 (48-55) | val 64 (56-59)
// R8: occupancy attack. Evidence: every prior version ran 1024 blocks = 16
// waves/CU (Occ 35-44%) and stalled ~65% of issue slots regardless of
// pipeline depth/atomics/channels (all falsified). R0's no-barrier no-LDS
// proj also took 110us -> TLP-starved, not structure-bound.
//  - 16 rows/block, 2048 blocks -> 8 blocks/CU, 32 waves/CU; <=64 VGPR cap.
//  - 2-kstep stage units (1 global_load_lds instr/lane, half the barriers),
//    3-slot ring, depth-2, vmcnt(5) ledger.
//  - interleaved hi/lo W2/E2 layouts (lo at imm offset) -> fewer VGPR/addr ops.
//  - k_red kernel (120 blocks) reduces 2048-block partials; k_topk reads wg2.
// ---------------------------------------------------------------------------

typedef short short8 __attribute__((ext_vector_type(8)));   // 8 bf16 = 4 VGPR
typedef float f32x4 __attribute__((ext_vector_type(4)));
typedef unsigned int uint4v __attribute__((ext_vector_type(4)));

__device__ __forceinline__ unsigned short f32_to_bf16(float f) {
  unsigned u = __float_as_uint(f);
  u += 0x7FFF + ((u >> 16) & 1);  // RNE
  return (unsigned short)(u >> 16);
}
__device__ __forceinline__ float bf16_to_f32(unsigned short h) {
  return __uint_as_float(((unsigned)h) << 16);
}

// packed f32->bf16 RNE, 2 at a time (hw instruction; low half = first operand)
__device__ __forceinline__ unsigned cvt_pk_bf16(float a, float b) {
  unsigned r;
  asm("v_cvt_pk_bf16_f32 %0, %1, %2" : "=v"(r) : "v"(a), "v"(b));
  return r;
}

// split 8 f32 -> hi/lo bf16 frags (hi = RNE(v), lo = RNE(v - hi))
__device__ __forceinline__ void split8v(const f32x4& v0, const f32x4& v1,
                                        short8& hi, short8& lo) {
  unsigned hp[4], lp[4];
#pragma unroll
  for (int j = 0; j < 4; ++j) {
    float a = (j < 2) ? v0[2 * j] : v1[2 * j - 4];
    float b = (j < 2) ? v0[2 * j + 1] : v1[2 * j - 3];
    unsigned p = cvt_pk_bf16(a, b);
    float ra = a - __uint_as_float(p << 16);
    float rb = b - __uint_as_float(p & 0xFFFF0000u);
    hp[j] = p;
    lp[j] = cvt_pk_bf16(ra, rb);
  }
  hi = __builtin_bit_cast(short8, (uint4v){hp[0], hp[1], hp[2], hp[3]});
  lo = __builtin_bit_cast(short8, (uint4v){lp[0], lp[1], lp[2], lp[3]});
}

#define MFMA(a, b, c) __builtin_amdgcn_mfma_f32_16x16x32_bf16(a, b, c, 0, 0, 0)
#define WAITVM(n) asm volatile("s_waitcnt vmcnt(" #n ")" ::: "memory")

typedef const __attribute__((address_space(1))) unsigned int guint;
typedef __attribute__((address_space(3))) unsigned int luint;
// async global->LDS, 16 B per lane; LDS dest = wave-uniform base + lane*16
__device__ __forceinline__ void stage16(const float* g, float* l) {
  __builtin_amdgcn_global_load_lds((guint*)g, (luint*)l, 16, 0, 0);
}
__device__ __forceinline__ void bar() {
  asm volatile("" ::: "memory");
  __builtin_amdgcn_s_barrier();
  asm volatile("" ::: "memory");
}

// ---- k_prep: split proj_w -> W2 (frag-interleaved); normalize emb -> E2 ----
// W2[col][ks][q][h][8]: idx = col*2048 + ks*64 + q*16 + h*8 + j  (halves)
// E2[n][kq][h][8]:      idx = n*128 + kq*16 + h*8 + j            (halves)
__global__ __launch_bounds__(256) void k_prep(const float* __restrict__ pw,
                                              const float* __restrict__ emb,
                                              unsigned short* __restrict__ W2,
                                              unsigned short* __restrict__ E2) {
  int tid = blockIdx.x * 256 + threadIdx.x;
  for (int i = tid; i < 65536; i += gridDim.x * 256) {
    float v = pw[i];
    unsigned short h = f32_to_bf16(v);
    int col = i >> 10, d = i & 1023;
    int ks = d >> 5, q = (d >> 3) & 3, j = d & 7;
    int idx = col * 2048 + ks * 64 + q * 16 + j;
    W2[idx] = h;
    W2[idx + 8] = f32_to_bf16(v - bf16_to_f32(h));
  }
  int wid = tid >> 6, lane = tid & 63;
  int nw = gridDim.x * 4;
  for (int n = wid; n < 960; n += nw) {
    float v = emb[n * 64 + lane];
    float s = v * v;
#pragma unroll
    for (int off = 1; off < 64; off <<= 1) s += __shfl_xor(s, off);
    float vn = v / sqrtf(s);
    unsigned short h = f32_to_bf16(vn);
    int idx = n * 128 + (lane >> 3) * 16 + (lane & 7);
    E2[idx] = h;
    E2[idx + 8] = f32_to_bf16(vn - bf16_to_f32(h));
  }
}

// ---- k_main: fused proj (x@W^T+b) + agg; 16 rows/block, 2048 blocks ----
__global__ __launch_bounds__(256, 8) void k_main(
    const float* __restrict__ x, const unsigned short* __restrict__ W2,
    const float* __restrict__ pb, const unsigned short* __restrict__ E2,
    const float* __restrict__ imp, float* __restrict__ pp) {
  __shared__ __align__(16) float xt[3][16][64];           // 12 KiB ring (3 slots)
  __shared__ __align__(16) unsigned short hxh[16][64];    // 2 KiB h hi
  __shared__ __align__(16) unsigned short hxl[16][64];    // 2 KiB h lo
  __shared__ float zpart[4][16][4];
  __shared__ float coefL[16][4];

  const int tid = threadIdx.x, w = tid >> 6, lane = tid & 63;
  const int q = lane >> 4, c = lane & 15;
  const int row0 = blockIdx.x * 16;
  const int nt0 = w;
  const int uoff = blockIdx.x & 15;   // per-block unit-phase rotation

  // staging: unit = 2 ksteps = 16 rows x 64 floats = 4KB; thread t covers
  // row t>>4, phys 16B-slot p=t&15.  Swizzle: logical slot l of row r lives
  // at phys (l&8)|((l&7)^(r&7)); source col pre-swizzled, LDS dest linear.
  const int srow = tid >> 4;
  const int p16 = tid & 15;
  const int lslot = (p16 & 8) | ((p16 & 7) ^ (srow & 7));
  const float* sbase = x + (size_t)(row0 + srow) * 1024 + lslot * 4;
  auto STAGEX = [&](int slot, int u) {
    int up = (u + uoff) & 15;
    stage16(sbase + up * 64, &xt[slot][0][0] + (w << 8));  // wave base: w*1KiB
  };

  // proj B fragments: base + imm-structured offsets (hi at +0, lo at +8)
  const unsigned short* bw = W2 + (size_t)(nt0 * 16 + c) * 2048 + q * 16;

  f32x4 acc = {0.f, 0.f, 0.f, 0.f};

  // swizzled read offsets for parity e: byte = c*256 + phys*16,
  // phys = e*8 | ((q*2 [+1]) ^ (c&7));  e=1 is +128 bytes.
  const unsigned o0a = (unsigned)(c * 256 + (((q * 2) ^ (c & 7)) << 4));
  const unsigned o0b = (unsigned)(c * 256 + (((q * 2 + 1) ^ (c & 7)) << 4));
  const char* xbase = (const char*)&xt[0][0][0];

  int rs = 0, wsl = 2;
  auto projstep2 = [&](short8 (&bh)[2], short8 (&bl)[2]) {
    const char* bp = xbase + rs * 4096;
    f32x4 a0 = *(const f32x4*)(bp + o0a);
    f32x4 a1 = *(const f32x4*)(bp + o0b);
    short8 ah, al;
    split8v(a0, a1, ah, al);
    acc = MFMA(ah, bh[0], acc);
    acc = MFMA(ah, bl[0], acc);
    acc = MFMA(al, bh[0], acc);
    a0 = *(const f32x4*)(bp + o0a + 128);
    a1 = *(const f32x4*)(bp + o0b + 128);
    split8v(a0, a1, ah, al);
    acc = MFMA(ah, bh[1], acc);
    acc = MFMA(ah, bl[1], acc);
    acc = MFMA(al, bh[1], acc);
    ++rs; if (rs == 3) rs = 0;
  };
  auto loadB = [&](short8 (&h)[2], short8 (&l)[2], int u) {  // unit u: ks 2u,2u+1
    int ku = (u + uoff) & 15;
    const unsigned short* f = bw + ku * 128;
    h[0] = *(const short8*)(f);
    l[0] = *(const short8*)(f + 8);
    h[1] = *(const short8*)(f + 64);
    l[1] = *(const short8*)(f + 72);
  };

  // ---------------- proj: 16 units (32 ksteps), 3-slot ring, depth-2 -------
  // Steady unit u: [loadB(u+1):4][WAITVM(5); bar; STAGE(u+2); proj 2u,2u+1].
  // At the wait, newest 5 = loadB(u+1)+S(u+1) -> retires S(u)+B(u) exactly.
  short8 BhA[2], BlA[2], BhB[2], BlB[2];
  loadB(BhA, BlA, 0);
  STAGEX(0, 0); STAGEX(1, 1);
  auto unit = [&](int u, short8 (&ch)[2], short8 (&cl)[2],
                  short8 (&nh)[2], short8 (&nl)[2]) {
    loadB(nh, nl, u + 1);
    WAITVM(5); bar();
    STAGEX(wsl, u + 2); ++wsl; if (wsl == 3) wsl = 0;
    projstep2(ch, cl);
  };
  unit(0, BhA, BlA, BhB, BlB);  unit(1, BhB, BlB, BhA, BlA);
  unit(2, BhA, BlA, BhB, BlB);  unit(3, BhB, BlB, BhA, BlA);
  unit(4, BhA, BlA, BhB, BlB);  unit(5, BhB, BlB, BhA, BlA);
  unit(6, BhA, BlA, BhB, BlB);  unit(7, BhB, BlB, BhA, BlA);
  unit(8, BhA, BlA, BhB, BlB);  unit(9, BhB, BlB, BhA, BlA);
  unit(10, BhA, BlA, BhB, BlB); unit(11, BhB, BlB, BhA, BlA);
  unit(12, BhA, BlA, BhB, BlB); unit(13, BhB, BlB, BhA, BlA);
  // u=14: cur=A(holds B14); load B15; no new stage (S15 was last).
  loadB(BhB, BlB, 15);
  WAITVM(5); bar(); projstep2(BhA, BlA);   // retires S14+B14
  // u=15
  WAITVM(0); bar(); projstep2(BhB, BlB);   // retires S15+B15

  // ---------------- h epilogue -> swizzled LDS exchange ----------------
  float bias = pb[nt0 * 16 + c];
#pragma unroll
  for (int r = 0; r < 4; ++r) {
    float val = acc[r] + bias;  // C: row=(q*4+r), col=c
    int row = q * 4 + r;
    unsigned colb = (unsigned)((nt0 * 16 + c) * 2);
    unsigned o = (unsigned)(row * 128) + (colb ^ ((unsigned)(row & 7) << 4));
    unsigned short h = f32_to_bf16(val);
    *(unsigned short*)((char*)&hxh[0][0] + o) = h;
    *(unsigned short*)((char*)&hxl[0][0] + o) = f32_to_bf16(val - bf16_to_f32(h));
  }
  __syncthreads();

  // agg A-frags (persist in VGPRs for both passes); row = c
  short8 Ahi[2], Alo[2];
  {
    unsigned rsw = (unsigned)((c & 7) << 4);
#pragma unroll
    for (int k2 = 0; k2 < 2; ++k2) {
      unsigned o = (unsigned)(c * 128) + (((unsigned)(k2 * 64 + q * 16)) ^ rsw);
      Ahi[k2] = *(const short8*)((const char*)&hxh[0][0] + o);
      Alo[k2] = *(const short8*)((const char*)&hxl[0][0] + o);
    }
  }

  short8 eA[4], eB[4];
  auto LOADE = [&](short8 (&d)[4], int i) {
    const unsigned short* e = E2 + (size_t)((w + 4 * i) * 16 + c) * 128 + q * 16;
    d[0] = *(const short8*)(e);         // ehi k 0..31 frag
    d[1] = *(const short8*)(e + 64);    // ehi k 32..63 frag
    d[2] = *(const short8*)(e + 8);     // elo k 0..31 frag
    d[3] = *(const short8*)(e + 72);    // elo k 32..63 frag
  };
  // logits: two independent MFMA chains (2 + 4) then add
  auto logits = [&](short8 (&e)[4]) -> f32x4 {
    f32x4 la = {0.f, 0.f, 0.f, 0.f}, lb = {0.f, 0.f, 0.f, 0.f};
    la = MFMA(Ahi[0], e[0], la); la = MFMA(Ahi[1], e[1], la);
    lb = MFMA(Ahi[0], e[2], lb); lb = MFMA(Ahi[1], e[3], lb);
    lb = MFMA(Alo[0], e[0], lb); lb = MFMA(Alo[1], e[1], lb);
    return la + lb;
  };

  // ---------------- pass 1: segment Z (2-buffer e-prefetch) ----------------
  f32x4 zacc = {0.f, 0.f, 0.f, 0.f};
  auto zflush = [&](int seg) {
#pragma unroll
    for (int r = 0; r < 4; ++r) {
      float v = zacc[r];
      v += __shfl_xor(v, 1); v += __shfl_xor(v, 2);
      v += __shfl_xor(v, 4); v += __shfl_xor(v, 8);
      if (c == 0) zpart[w][q * 4 + r][seg] = v;
    }
    zacc = (f32x4){0.f, 0.f, 0.f, 0.f};
  };

  int cur_seg = 0;
  auto step1 = [&](int i, short8 (&e)[4]) {
    int nt = w + 4 * i;
    int s = (nt < 32) ? 0 : (nt < 48) ? 1 : (nt < 56) ? 2 : 3;
    if (s != cur_seg) { zflush(cur_seg); cur_seg = s; }
    f32x4 l = logits(e);
#pragma unroll
    for (int r = 0; r < 4; ++r) zacc[r] += __expf(l[r]);
  };
  LOADE(eA, 0);
#pragma unroll 1
  for (int j = 0; j < 7; ++j) {
    LOADE(eB, 2 * j + 1); step1(2 * j, eA);
    LOADE(eA, 2 * j + 2); step1(2 * j + 1, eB);
  }
  step1(14, eA);
  zflush(cur_seg);
  __syncthreads();
  if (tid < 64) {  // combine: 64 threads = 16 rows x 4 segs
    int row = tid & 15, sg = tid >> 4;
    float Z = zpart[0][row][sg] + zpart[1][row][sg] + zpart[2][row][sg] + zpart[3][row][sg];
    coefL[row][sg] = imp[row0 + row] / Z;
  }
  __syncthreads();

  // ---------------- pass 2: weighted exp accumulation -> per-block partials --
  float* ppb = pp + (size_t)blockIdx.x * 960;
  f32x4 cf;
  int cs2 = -1;
  auto step2 = [&](int i, short8 (&e)[4]) {
    int nt = w + 4 * i;
    int s = (nt < 32) ? 0 : (nt < 48) ? 1 : (nt < 56) ? 2 : 3;
    if (s != cs2) {
#pragma unroll
      for (int r = 0; r < 4; ++r) cf[r] = coefL[q * 4 + r][s];
      cs2 = s;
    }
    f32x4 l = logits(e);
    float wsum = 0.f;
#pragma unroll
    for (int r = 0; r < 4; ++r) wsum = fmaf(__expf(l[r]), cf[r], wsum);
    wsum += __shfl_xor(wsum, 16);
    wsum += __shfl_xor(wsum, 32);  // sum over all 16 rows (4 q-groups)
    if (lane < 16) ppb[nt * 16 + c] = wsum;  // plain store: each col once/block
  };
  LOADE(eA, 0);
#pragma unroll 1
  for (int j = 0; j < 7; ++j) {
    LOADE(eB, 2 * j + 1); step2(2 * j, eA);
    LOADE(eA, 2 * j + 2); step2(2 * j + 1, eB);
  }
  step2(14, eA);
}

// ---- k_red: reduce 2048-block partials -> wg2[8][960] ----
// grid 120 = 8 batches x 15 column-chunks of 64; 256 thr = 4 rb-quarters x 64 cols
__global__ __launch_bounds__(256) void k_red(const float* __restrict__ pp,
                                             float* __restrict__ wg2) {
  __shared__ float red[4][64];
  int bx = blockIdx.x, b = bx / 15, ch = bx % 15;
  int t = threadIdx.x, col = t & 63, rq = t >> 6;
  const float* p = pp + (size_t)(b * 256 + rq * 64) * 960 + ch * 64 + col;
  float s0 = 0.f, s1 = 0.f, s2 = 0.f, s3 = 0.f;
  for (int k = 0; k < 64; k += 4) {  // 4 chains
    s0 += p[(size_t)(k + 0) * 960];
    s1 += p[(size_t)(k + 1) * 960];
    s2 += p[(size_t)(k + 2) * 960];
    s3 += p[(size_t)(k + 3) * 960];
  }
  red[rq][col] = (s0 + s1) + (s2 + s3);
  __syncthreads();
  if (t < 64) wg2[b * 960 + ch * 64 + t] = red[0][t] + red[1][t] + red[2][t] + red[3][t];
}

// ---- k_topk: rank-based selection + ballot emission (reads wg2) ----
__global__ __launch_bounds__(256) void k_topk(const float* __restrict__ wg2,
                                              float* __restrict__ out) {
  __shared__ float vals[512];
  __shared__ int flags[512];
  int blk = blockIdx.x;
  int b = blk >> 2, t = blk & 3;
  int tid = threadIdx.x;
  const int Ns[4] = {512, 256, 128, 64};
  const int Ks[4] = {64, 32, 16, 3};
  const int Off[4] = {0, 512, 768, 896};
  int N = Ns[t], K = Ks[t], off = Off[t];
  for (int n = tid; n < N; n += 256) vals[n] = wg2[b * 960 + off + n];
  __syncthreads();
  for (int n = tid; n < N; n += 256) {
    float v = vals[n];
    int rank = 0;
    for (int m = 0; m < N; ++m) {  // LDS broadcast reads, fully parallel
      float u = vals[m];
      rank += (u > v || (u == v && m < n)) ? 1 : 0;
    }
    flags[n] = (rank < K) ? 1 : 0;
  }
  __syncthreads();
  if (t <= 1) {  // index outputs: sorted ascending via ballot prefix (wave 0)
    if (tid < 64) {
      int base = 0;
      for (int ch = 0; ch < N; ch += 64) {
        int n = ch + tid;
        int f = flags[n];
        unsigned long long mask = __ballot(f);
        if (f) {
          int pos = base + __popcll(mask & ((1ull << tid) - 1ull));
          if (t == 0) out[b * 64 + pos] = (float)n;
          else out[512 + b * 32 + pos] = (float)n;
        }
        base += __popcll(mask);
      }
    }
  } else if (t == 2) {  // rel_Q and rel_K (identical sparse vectors)
    for (int n = tid; n < 128; n += 256) {
      float v = flags[n] ? vals[n] : 0.f;
      out[768 + b * 128 + n] = v;
      out[1792 + b * 128 + n] = v;
    }
  } else {  // val_w
    for (int n = tid; n < 64; n += 256) {
      float v = flags[n] ? vals[n] : 0.f;
      out[2816 + b * 64 + n] = v;
    }
  }
}

extern "C" void kernel_launch(void* const* d_in, const int* in_sizes, int n_in,
                              void* d_out, int out_size, void* d_ws, size_t ws_size,
                              hipStream_t stream) {
  const float* x   = (const float*)d_in[0];   // 8*4096*1024
  const float* imp = (const float*)d_in[1];   // 8*4096
  const float* pw  = (const float*)d_in[2];   // 64*1024
  const float* pb  = (const float*)d_in[3];   // 64
  const float* emb = (const float*)d_in[4];   // 1216*64
  float* out = (float*)d_out;                 // 3328 floats

  char* ws = (char*)d_ws;
  unsigned short* W2 = (unsigned short*)(ws);              // 256 KiB
  unsigned short* E2 = (unsigned short*)(ws + 262144);     // 240 KiB
  float*          pp = (float*)(ws + 507904);              // 7.5 MiB partials
  float*         wg2 = (float*)(ws + 8372224);             // 30 KiB

  hipLaunchKernelGGL(k_prep, dim3(64), dim3(256), 0, stream, pw, emb, W2, E2);
  hipLaunchKernelGGL(k_main, dim3(2048), dim3(256), 0, stream, x, W2, pb, E2, imp, pp);
  hipLaunchKernelGGL(k_red,  dim3(120), dim3(256), 0, stream, pp, wg2);
  hipLaunchKernelGGL(k_topk, dim3(32), dim3(256), 0, stream, wg2, out);
}